// Round 2
// baseline (272.067 us; speedup 1.0000x reference)
//
#include <hip/hip_runtime.h>
#include <stdint.h>
#include <stddef.h>

// LSTMCell fused: z = [h|x] @ [Wh|Wx]^T + (Wh_b+Wx_b); s=sigmoid(z); g=tanh(z);
// c_new = s*(c+g); h_new = s*tanh(c_new). Outputs concat [h_new, c_new] fp32.
// B=8192, D_H=D_IN=1024, K_total=2048.

typedef __attribute__((ext_vector_type(8))) short bf16x8;
typedef __attribute__((ext_vector_type(4))) float f32x4;
typedef __attribute__((ext_vector_type(8))) unsigned short ushort8;

#define BATCH 8192
#define DH    1024
#define KTOT  2048

__device__ __forceinline__ unsigned short f2bf(float f) {
    unsigned int u = __float_as_uint(f);
    u += 0x7FFFu + ((u >> 16) & 1u);   // round-to-nearest-even
    return (unsigned short)(u >> 16);
}

// numerically stable tanh via exp of negative argument only (no inf/inf NaN)
__device__ __forceinline__ float tanh_fast(float v) {
    float a = fabsf(v);
    float e = __expf(-2.0f * a);
    float t = (1.0f - e) / (1.0f + e);
    return v < 0.0f ? -t : t;
}

__device__ __forceinline__ void gload_lds16(const void* g, void* l) {
    __builtin_amdgcn_global_load_lds(
        (const __attribute__((address_space(1))) void*)g,
        (__attribute__((address_space(3))) void*)l, 16, 0, 0);
}

// Concatenate two [rows][1024] fp32 matrices into one [rows][2048] bf16 matrix.
// Each thread converts 8 contiguous elements (always fully inside one source).
__global__ __launch_bounds__(256) void cast_cat_kernel(
    const float* __restrict__ s0, const float* __restrict__ s1,
    unsigned short* __restrict__ dst)
{
    unsigned int idx  = blockIdx.x * 256u + threadIdx.x;
    unsigned int base = idx * 8u;                 // element index into [rows][2048]
    unsigned int r    = base >> 11;
    unsigned int k    = base & 2047u;
    const float* src = (k < 1024u) ? (s0 + (size_t)r * 1024u + k)
                                   : (s1 + (size_t)r * 1024u + (k - 1024u));
    const float4* s4 = (const float4*)src;
    float4 f0 = s4[0], f1 = s4[1];
    ushort8 o;
    o[0] = f2bf(f0.x); o[1] = f2bf(f0.y); o[2] = f2bf(f0.z); o[3] = f2bf(f0.w);
    o[4] = f2bf(f1.x); o[5] = f2bf(f1.y); o[6] = f2bf(f1.z); o[7] = f2bf(f1.w);
    *(ushort8*)(dst + base) = o;
}

// 128x128 tile GEMM (m97 structure): C[b][n] = sum_k A[b][k]*W[n][k], fused epilogue.
// 256 threads = 4 waves (2x2), each wave does a 64x64 sub-tile as 4x4 of 16x16 frags.
#define BK 64
__global__ __launch_bounds__(256) void lstm_gemm_kernel(
    const unsigned short* __restrict__ A,   // [8192][2048] bf16
    const unsigned short* __restrict__ W,   // [1024][2048] bf16
    const float* __restrict__ Whb, const float* __restrict__ Wxb,
    const float* __restrict__ Cin,
    float* __restrict__ Hout, float* __restrict__ Cout)
{
    __shared__ unsigned short tA[128 * BK];   // 16 KiB
    __shared__ unsigned short tB[128 * BK];   // 16 KiB

    const int tid  = threadIdx.x;
    const int wid  = tid >> 6;
    const int lane = tid & 63;
    const int bidN = blockIdx.x & 7;     // 1024/128 = 8 col tiles
    const int bidM = blockIdx.x >> 3;    // 8192/128 = 64 row tiles
    const int row0 = bidM * 128;
    const int col0 = bidN * 128;
    const int wm = (wid >> 1) * 64;      // wave row offset in tile
    const int wn = (wid & 1) * 64;       // wave col offset in tile

    f32x4 acc[4][4] = {};

    const int lrow = lane >> 3;          // 0..7  (staging row within 8-row chunk)
    const int lcol = (lane & 7) * 8;     // 0..56 (staging k element)

    for (int kt = 0; kt < KTOT / BK; ++kt) {
        const int k0 = kt * BK;
        // stage A and W tiles: 16 chunks of 8 rows each, 4 chunks per wave
        #pragma unroll
        for (int i = 0; i < 4; ++i) {
            const int ch = wid * 4 + i;                       // 0..15
            const int rr = ch * 8 + lrow;                     // 0..127
            gload_lds16(A + (size_t)(row0 + rr) * KTOT + k0 + lcol, &tA[ch * 512]);
            gload_lds16(W + (size_t)(col0 + rr) * KTOT + k0 + lcol, &tB[ch * 512]);
        }
        __syncthreads();   // vmcnt(0) drained before barrier by compiler

        #pragma unroll
        for (int kk = 0; kk < 2; ++kk) {
            bf16x8 af[4], bfr[4];
            #pragma unroll
            for (int m = 0; m < 4; ++m)
                af[m] = *(const bf16x8*)&tA[(wm + m * 16 + (lane & 15)) * BK + kk * 32 + (lane >> 4) * 8];
            #pragma unroll
            for (int n = 0; n < 4; ++n)
                bfr[n] = *(const bf16x8*)&tB[(wn + n * 16 + (lane & 15)) * BK + kk * 32 + (lane >> 4) * 8];
            #pragma unroll
            for (int m = 0; m < 4; ++m)
                #pragma unroll
                for (int n = 0; n < 4; ++n)
                    acc[m][n] = __builtin_amdgcn_mfma_f32_16x16x32_bf16(af[m], bfr[n], acc[m][n], 0, 0, 0);
        }
        __syncthreads();
    }

    // epilogue: z -> (h_new, c_new)
    const int rlo = (lane >> 4) * 4;
    const int cc  = lane & 15;
    #pragma unroll
    for (int n = 0; n < 4; ++n) {
        const int col  = col0 + wn + n * 16 + cc;
        const float bias = Whb[col] + Wxb[col];
        #pragma unroll
        for (int m = 0; m < 4; ++m) {
            #pragma unroll
            for (int j = 0; j < 4; ++j) {
                const int row = row0 + wm + m * 16 + rlo + j;
                const size_t off = (size_t)row * DH + col;
                const float z = acc[m][n][j] + bias;
                const float s = 0.5f + 0.5f * tanh_fast(0.5f * z);  // sigmoid(z)
                const float g = tanh_fast(z);
                const float cn = s * (Cin[off] + g);
                const float hn = s * tanh_fast(cn);
                Hout[off] = hn;
                Cout[off] = cn;
            }
        }
    }
}

// fp32 fallback (only used if workspace is too small for bf16 staging)
__global__ __launch_bounds__(256) void lstm_naive_kernel(
    const float* __restrict__ x, const float* __restrict__ h,
    const float* __restrict__ c,
    const float* __restrict__ Whw, const float* __restrict__ Whb,
    const float* __restrict__ Wxw, const float* __restrict__ Wxb,
    float* __restrict__ Hout, float* __restrict__ Cout)
{
    const int idx = blockIdx.x * 256 + threadIdx.x;
    const int b = idx >> 10, n = idx & 1023;
    const float* hr = h  + (size_t)b * 1024;
    const float* xr = x  + (size_t)b * 1024;
    const float* wh = Whw + (size_t)n * 1024;
    const float* wx = Wxw + (size_t)n * 1024;
    float z = Whb[n] + Wxb[n];
    for (int k = 0; k < 1024; ++k) z += hr[k] * wh[k] + xr[k] * wx[k];
    const float s = 0.5f + 0.5f * tanh_fast(0.5f * z);
    const float g = tanh_fast(z);
    const size_t off = (size_t)b * 1024 + n;
    const float cn = s * (c[off] + g);
    Hout[off] = s * tanh_fast(cn);
    Cout[off] = cn;
}

extern "C" void kernel_launch(void* const* d_in, const int* in_sizes, int n_in,
                              void* d_out, int out_size, void* d_ws, size_t ws_size,
                              hipStream_t stream) {
    const float* x   = (const float*)d_in[0];
    const float* h   = (const float*)d_in[1];
    const float* c   = (const float*)d_in[2];
    const float* Whw = (const float*)d_in[3];
    const float* Whb = (const float*)d_in[4];
    const float* Wxw = (const float*)d_in[5];
    const float* Wxb = (const float*)d_in[6];
    float* Hout = (float*)d_out;
    float* Cout = Hout + (size_t)BATCH * DH;

    const size_t needA = (size_t)BATCH * KTOT * 2;   // 32 MiB
    const size_t needW = (size_t)DH * KTOT * 2;      //  4 MiB

    if (ws_size >= needA + needW) {
        unsigned short* Abf = (unsigned short*)d_ws;
        unsigned short* Wbf = (unsigned short*)((char*)d_ws + needA);
        // A = bf16([h | x])  : 8192*2048/8/256 = 8192 blocks
        cast_cat_kernel<<<8192, 256, 0, stream>>>(h, x, Abf);
        // W = bf16([Wh | Wx]): 1024*2048/8/256 = 1024 blocks
        cast_cat_kernel<<<1024, 256, 0, stream>>>(Whw, Wxw, Wbf);
        // GEMM + fused epilogue: (8192/128)*(1024/128) = 512 blocks
        lstm_gemm_kernel<<<512, 256, 0, stream>>>(Abf, Wbf, Whb, Wxb, c, Hout, Cout);
    } else {
        lstm_naive_kernel<<<(BATCH * DH) / 256, 256, 0, stream>>>(
            x, h, c, Whw, Whb, Wxw, Wxb, Hout, Cout);
    }
}

// Round 3
// 224.410 us; speedup vs baseline: 1.2124x; 1.2124x over previous
//
#include <hip/hip_runtime.h>
#include <stdint.h>
#include <stddef.h>

// LSTMCell fused: z = [h|x] @ [Wh|Wx]^T + (Wh_b+Wx_b); s=sigmoid(z); g=tanh(z);
// c_new = s*(c+g); h_new = s*tanh(c_new). Outputs concat [h_new, c_new] fp32.
// B=8192, D_H=D_IN=1024, K_total=2048.
//
// GEMM: BM=256 x BN=128 x BK=64, 512 thr (8 waves 2Mx4N), grid 256 = 1 block/CU.
// 8-phase-style schedule (T2 swizzle + T3 phases + T4 counted vmcnt + T5 setprio),
// 3-slot rolling LDS (144 KiB dynamic) so prefetch of tile kt+2 stays in flight
// across barriers while computing tile kt.

typedef __attribute__((ext_vector_type(8))) short bf16x8;
typedef __attribute__((ext_vector_type(4))) float f32x4;
typedef __attribute__((ext_vector_type(8))) unsigned short ushort8;

#define BATCH 8192
#define DH    1024
#define KTOT  2048
#define NKT   32          // KTOT / 64
#define ASLOT 16384       // 256*64 shorts per A slot
#define BSLOT 8192        // 128*64 shorts per B slot
#define LDS_BYTES ((3*ASLOT + 3*BSLOT) * 2)   // 147456

__device__ __forceinline__ unsigned short f2bf(float f) {
    unsigned int u = __float_as_uint(f);
    u += 0x7FFFu + ((u >> 16) & 1u);   // round-to-nearest-even
    return (unsigned short)(u >> 16);
}

__device__ __forceinline__ float tanh_fast(float v) {
    float a = fabsf(v);
    float e = __expf(-2.0f * a);
    float t = (1.0f - e) / (1.0f + e);
    return v < 0.0f ? -t : t;
}

__device__ __forceinline__ void gload_lds16(const void* g, void* l) {
    __builtin_amdgcn_global_load_lds(
        (const __attribute__((address_space(1))) void*)g,
        (__attribute__((address_space(3))) void*)l, 16, 0, 0);
}

// One cast kernel for A=bf16([h|x]) (8192x2048) and W=bf16([Wh|Wx]) (1024x2048).
#define A_CHUNKS 2097152u
#define W_CHUNKS 262144u
__global__ __launch_bounds__(256) void cast_all_kernel(
    const float* __restrict__ h, const float* __restrict__ x,
    const float* __restrict__ Whw, const float* __restrict__ Wxw,
    unsigned short* __restrict__ Abf, unsigned short* __restrict__ Wbf)
{
    for (unsigned c = blockIdx.x * 256u + threadIdx.x;
         c < A_CHUNKS + W_CHUNKS; c += gridDim.x * 256u) {
        const float* src;
        unsigned short* dst;
        if (c < A_CHUNKS) {
            unsigned base = c * 8u, r = base >> 11, k = base & 2047u;
            src = (k < 1024u) ? (h + (size_t)r * 1024u + k)
                              : (x + (size_t)r * 1024u + (k - 1024u));
            dst = Abf + base;
        } else {
            unsigned c2 = c - A_CHUNKS;
            unsigned base = c2 * 8u, r = base >> 11, k = base & 2047u;
            src = (k < 1024u) ? (Whw + (size_t)r * 1024u + k)
                              : (Wxw + (size_t)r * 1024u + (k - 1024u));
            dst = Wbf + base;
        }
        const float4* s4 = (const float4*)src;
        float4 f0 = s4[0], f1 = s4[1];
        ushort8 o;
        o[0]=f2bf(f0.x); o[1]=f2bf(f0.y); o[2]=f2bf(f0.z); o[3]=f2bf(f0.w);
        o[4]=f2bf(f1.x); o[5]=f2bf(f1.y); o[6]=f2bf(f1.z); o[7]=f2bf(f1.w);
        *(ushort8*)dst = o;
    }
}

// One phase: ds_read frags (swizzled) -> mid (stage issue / vmcnt gate) ->
// barrier -> lgkmcnt(0) -> setprio(1) -> 8 MFMA -> setprio(0) -> barrier.
template <int KK, int MG, bool READB, typename F>
__device__ __forceinline__ void phase_fn(
    const unsigned short* As, const unsigned short* Bs,
    int wr, int wc, int ln15, int hi, int ln7,
    f32x4 (&acc)[8][2], bf16x8 (&bfr)[2], F&& mid)
{
    bf16x8 af[4];
    #pragma unroll
    for (int i = 0; i < 4; ++i) {
        int r = wr * 128 + (MG * 4 + i) * 16 + ln15;
        af[i] = *(const bf16x8*)(As + r * 64 + (((KK * 4 + hi) ^ ln7) * 8));
    }
    if constexpr (READB) {
        #pragma unroll
        for (int n = 0; n < 2; ++n) {
            int r = wc * 32 + n * 16 + ln15;
            bfr[n] = *(const bf16x8*)(Bs + r * 64 + (((KK * 4 + hi) ^ ln7) * 8));
        }
    }
    mid();
    __builtin_amdgcn_s_barrier();
    asm volatile("s_waitcnt lgkmcnt(0)" ::: "memory");
    __builtin_amdgcn_sched_barrier(0);
    __builtin_amdgcn_s_setprio(1);
    #pragma unroll
    for (int i = 0; i < 4; ++i)
        #pragma unroll
        for (int n = 0; n < 2; ++n)
            acc[MG * 4 + i][n] = __builtin_amdgcn_mfma_f32_16x16x32_bf16(
                af[i], bfr[n], acc[MG * 4 + i][n], 0, 0, 0);
    __builtin_amdgcn_s_setprio(0);
    __builtin_amdgcn_s_barrier();
}

__global__ __launch_bounds__(512, 2) void lstm_gemm_kernel(
    const unsigned short* __restrict__ A,   // [8192][2048] bf16
    const unsigned short* __restrict__ W,   // [1024][2048] bf16
    const float* __restrict__ Whb, const float* __restrict__ Wxb,
    const float* __restrict__ Cin,
    float* __restrict__ Hout, float* __restrict__ Cout)
{
    extern __shared__ unsigned short smem[];
    unsigned short* sA = smem;               // 3 slots of 256x64
    unsigned short* sB = smem + 3 * ASLOT;   // 3 slots of 128x64

    const int tid  = threadIdx.x;
    const int wid  = tid >> 6;
    const int lane = tid & 63;
    const int wr = wid >> 2, wc = wid & 3;          // 2M x 4N waves
    const int bidN = blockIdx.x & 7;                // 1024/128 = 8
    const int bidM = blockIdx.x >> 3;               // 8192/256 = 32
    const int row0 = bidM * 256, col0 = bidN * 128;
    const int ln15 = lane & 15, hi = lane >> 4, ln7 = lane & 7;

    const unsigned short* Ag = A + (size_t)row0 * KTOT;
    const unsigned short* Bg = W + (size_t)col0 * KTOT;

    f32x4 acc[8][2] = {};
    bf16x8 bfr[2];

    // Stage one 128-row x 64-col unit: linear LDS dest (gload_lds lane x 16B),
    // inverse-swizzled global source (physical slot p holds logical slot p^(r&7)).
    auto stage = [&](const unsigned short* gbase, unsigned short* lbase) {
        #pragma unroll
        for (int j = 0; j < 2; ++j) {
            int c = j * 512 + tid;
            int r = c >> 3, p = c & 7;
            const unsigned short* g = gbase + (size_t)r * KTOT + ((p ^ (r & 7)) * 8);
            unsigned short* l = lbase + (size_t)(j * 512 + wid * 64) * 8;  // wave-uniform
            gload_lds16(g, l);
        }
    };

    // Prologue: tile 0 -> slot 0, tile 1 -> slot 1 (12 loads/thread), gate tile 0.
    stage(Ag,                         sA);
    stage(Ag + (size_t)128 * KTOT,    sA + 8192);
    stage(Bg,                         sB);
    stage(Ag + 64,                    sA + ASLOT);
    stage(Ag + (size_t)128 * KTOT + 64, sA + ASLOT + 8192);
    stage(Bg + 64,                    sB + BSLOT);
    asm volatile("s_waitcnt vmcnt(6)" ::: "memory");
    __builtin_amdgcn_s_barrier();

    int scur = 0, swr = 2;
    for (int kt = 0; kt < NKT; ++kt) {
        const unsigned short* As = sA + scur * ASLOT;
        const unsigned short* Bs = sB + scur * BSLOT;
        unsigned short* Aw = sA + swr * ASLOT;
        unsigned short* Bw = sB + swr * BSLOT;
        const size_t kn = (size_t)(kt + 2) * 64;
        const bool pre = (kt < NKT - 2);

        phase_fn<0, 0, true >(As, Bs, wr, wc, ln15, hi, ln7, acc, bfr,
            [&] { if (pre) stage(Ag + kn, Aw); });
        phase_fn<0, 1, false>(As, Bs, wr, wc, ln15, hi, ln7, acc, bfr,
            [&] { if (pre) stage(Ag + (size_t)128 * KTOT + kn, Aw + 8192); });
        phase_fn<1, 0, true >(As, Bs, wr, wc, ln15, hi, ln7, acc, bfr,
            [&] { if (pre) stage(Bg + kn, Bw); });
        phase_fn<1, 1, false>(As, Bs, wr, wc, ln15, hi, ln7, acc, bfr,
            [&] {
                if (kt < NKT - 2)       asm volatile("s_waitcnt vmcnt(6)" ::: "memory");
                else if (kt == NKT - 2) asm volatile("s_waitcnt vmcnt(0)" ::: "memory");
            });

        scur = (scur == 2) ? 0 : scur + 1;
        swr  = (swr  == 2) ? 0 : swr  + 1;
    }

    // Epilogue: z -> (h_new, c_new). C/D map: col=lane&15, row=(lane>>4)*4+j.
    const int rlo = hi * 4;
    #pragma unroll
    for (int n = 0; n < 2; ++n) {
        const int col = col0 + wc * 32 + n * 16 + ln15;
        const float bias = Whb[col] + Wxb[col];
        #pragma unroll
        for (int m = 0; m < 8; ++m) {
            #pragma unroll
            for (int j = 0; j < 4; ++j) {
                const int row = row0 + wr * 128 + m * 16 + rlo + j;
                const size_t off = (size_t)row * DH + col;
                const float z = acc[m][n][j] + bias;
                const float s = 0.5f + 0.5f * tanh_fast(0.5f * z);  // sigmoid(z)
                const float g = tanh_fast(z);
                const float cn = s * (Cin[off] + g);
                Hout[off] = s * tanh_fast(cn);
                Cout[off] = cn;
            }
        }
    }
}

// fp32 fallback (only if workspace too small for bf16 staging)
__global__ __launch_bounds__(256) void lstm_naive_kernel(
    const float* __restrict__ x, const float* __restrict__ h,
    const float* __restrict__ c,
    const float* __restrict__ Whw, const float* __restrict__ Whb,
    const float* __restrict__ Wxw, const float* __restrict__ Wxb,
    float* __restrict__ Hout, float* __restrict__ Cout)
{
    const int idx = blockIdx.x * 256 + threadIdx.x;
    const int b = idx >> 10, n = idx & 1023;
    const float* hr = h  + (size_t)b * 1024;
    const float* xr = x  + (size_t)b * 1024;
    const float* wh = Whw + (size_t)n * 1024;
    const float* wx = Wxw + (size_t)n * 1024;
    float z = Whb[n] + Wxb[n];
    for (int k = 0; k < 1024; ++k) z += hr[k] * wh[k] + xr[k] * wx[k];
    const float s = 0.5f + 0.5f * tanh_fast(0.5f * z);
    const float g = tanh_fast(z);
    const size_t off = (size_t)b * 1024 + n;
    const float cn = s * (c[off] + g);
    Hout[off] = s * tanh_fast(cn);
    Cout[off] = cn;
}

extern "C" void kernel_launch(void* const* d_in, const int* in_sizes, int n_in,
                              void* d_out, int out_size, void* d_ws, size_t ws_size,
                              hipStream_t stream) {
    const float* x   = (const float*)d_in[0];
    const float* h   = (const float*)d_in[1];
    const float* c   = (const float*)d_in[2];
    const float* Whw = (const float*)d_in[3];
    const float* Whb = (const float*)d_in[4];
    const float* Wxw = (const float*)d_in[5];
    const float* Wxb = (const float*)d_in[6];
    float* Hout = (float*)d_out;
    float* Cout = Hout + (size_t)BATCH * DH;

    const size_t needA = (size_t)BATCH * KTOT * 2;   // 32 MiB
    const size_t needW = (size_t)DH * KTOT * 2;      //  4 MiB

    if (ws_size >= needA + needW) {
        unsigned short* Abf = (unsigned short*)d_ws;
        unsigned short* Wbf = (unsigned short*)((char*)d_ws + needA);
        cast_all_kernel<<<2304, 256, 0, stream>>>(h, x, Whw, Wxw, Abf, Wbf);
        (void)hipFuncSetAttribute((const void*)lstm_gemm_kernel,
                                  hipFuncAttributeMaxDynamicSharedMemorySize,
                                  LDS_BYTES);
        lstm_gemm_kernel<<<256, 512, LDS_BYTES, stream>>>(
            Abf, Wbf, Whb, Wxb, c, Hout, Cout);
    } else {
        lstm_naive_kernel<<<(BATCH * DH) / 256, 256, 0, stream>>>(
            x, h, c, Whw, Whb, Wxw, Wxb, Hout, Cout);
    }
}

// Round 4
// 222.351 us; speedup vs baseline: 1.2236x; 1.0093x over previous
//
#include <hip/hip_runtime.h>
#include <stdint.h>
#include <stddef.h>

// LSTMCell fused: z = [h|x] @ [Wh|Wx]^T + (Wh_b+Wx_b); s=sigmoid(z); g=tanh(z);
// c_new = s*(c+g); h_new = s*tanh(c_new). Outputs concat [h_new, c_new] fp32.
// B=8192, D_H=D_IN=1024, K_total=2048.
//
// GEMM: BM=256 x BN=128 x BK=64, 512 thr (8 waves 2Mx4N), grid 256 = 1 block/CU.
// 2 phases/K-tile x 16 MFMA each; T2 LDS XOR-swizzle (0 bank conflicts, verified r3);
// T4 counted vmcnt(6) w/ 3-slot rolling LDS; T5 setprio; T1 XCD-grouped block
// swizzle so the 8 blocks sharing an A-panel land on ONE XCD's L2 (r3 showed
// 159 MB FETCH vs 68 MB minimum from cross-XCD A-panel re-fetch).

typedef __attribute__((ext_vector_type(8))) short bf16x8;
typedef __attribute__((ext_vector_type(4))) float f32x4;
typedef __attribute__((ext_vector_type(8))) unsigned short ushort8;

#define BATCH 8192
#define DH    1024
#define KTOT  2048
#define NKT   32          // KTOT / 64
#define ASLOT 16384       // 256*64 shorts per A slot
#define BSLOT 8192        // 128*64 shorts per B slot
#define LDS_BYTES ((3*ASLOT + 3*BSLOT) * 2)   // 147456

__device__ __forceinline__ unsigned short f2bf(float f) {
    unsigned int u = __float_as_uint(f);
    u += 0x7FFFu + ((u >> 16) & 1u);   // round-to-nearest-even
    return (unsigned short)(u >> 16);
}

__device__ __forceinline__ float tanh_fast(float v) {
    float a = fabsf(v);
    float e = __expf(-2.0f * a);
    float t = (1.0f - e) / (1.0f + e);
    return v < 0.0f ? -t : t;
}

__device__ __forceinline__ void gload_lds16(const void* g, void* l) {
    __builtin_amdgcn_global_load_lds(
        (const __attribute__((address_space(1))) void*)g,
        (__attribute__((address_space(3))) void*)l, 16, 0, 0);
}

// One cast kernel for A=bf16([h|x]) (8192x2048) and W=bf16([Wh|Wx]) (1024x2048).
#define A_CHUNKS 2097152u
#define W_CHUNKS 262144u
__global__ __launch_bounds__(256) void cast_all_kernel(
    const float* __restrict__ h, const float* __restrict__ x,
    const float* __restrict__ Whw, const float* __restrict__ Wxw,
    unsigned short* __restrict__ Abf, unsigned short* __restrict__ Wbf)
{
    for (unsigned c = blockIdx.x * 256u + threadIdx.x;
         c < A_CHUNKS + W_CHUNKS; c += gridDim.x * 256u) {
        const float* src;
        unsigned short* dst;
        if (c < A_CHUNKS) {
            unsigned base = c * 8u, r = base >> 11, k = base & 2047u;
            src = (k < 1024u) ? (h + (size_t)r * 1024u + k)
                              : (x + (size_t)r * 1024u + (k - 1024u));
            dst = Abf + base;
        } else {
            unsigned c2 = c - A_CHUNKS;
            unsigned base = c2 * 8u, r = base >> 11, k = base & 2047u;
            src = (k < 1024u) ? (Whw + (size_t)r * 1024u + k)
                              : (Wxw + (size_t)r * 1024u + (k - 1024u));
            dst = Wbf + base;
        }
        const float4* s4 = (const float4*)src;
        float4 f0 = s4[0], f1 = s4[1];
        ushort8 o;
        o[0]=f2bf(f0.x); o[1]=f2bf(f0.y); o[2]=f2bf(f0.z); o[3]=f2bf(f0.w);
        o[4]=f2bf(f1.x); o[5]=f2bf(f1.y); o[6]=f2bf(f1.z); o[7]=f2bf(f1.w);
        *(ushort8*)dst = o;
    }
}

// One phase: ds_read 8 A-frags + 2 B-frags (swizzled) -> mid (stage / vmcnt) ->
// barrier -> lgkmcnt(0) -> setprio(1) -> 16 MFMA -> setprio(0) -> barrier.
template <int KK, typename F>
__device__ __forceinline__ void phase_fn(
    const unsigned short* As, const unsigned short* Bs,
    int wr, int wc, int ln15, int hi, int ln7,
    f32x4 (&acc)[8][2], F&& mid)
{
    bf16x8 af[8], bfr[2];
    #pragma unroll
    for (int m = 0; m < 8; ++m) {
        int r = wr * 128 + m * 16 + ln15;        // r&7 == ln7
        af[m] = *(const bf16x8*)(As + r * 64 + (((KK * 4 + hi) ^ ln7) * 8));
    }
    #pragma unroll
    for (int n = 0; n < 2; ++n) {
        int r = wc * 32 + n * 16 + ln15;
        bfr[n] = *(const bf16x8*)(Bs + r * 64 + (((KK * 4 + hi) ^ ln7) * 8));
    }
    mid();
    __builtin_amdgcn_s_barrier();
    asm volatile("s_waitcnt lgkmcnt(0)" ::: "memory");
    __builtin_amdgcn_sched_barrier(0);
    __builtin_amdgcn_s_setprio(1);
    #pragma unroll
    for (int m = 0; m < 8; ++m)
        #pragma unroll
        for (int n = 0; n < 2; ++n)
            acc[m][n] = __builtin_amdgcn_mfma_f32_16x16x32_bf16(
                af[m], bfr[n], acc[m][n], 0, 0, 0);
    __builtin_amdgcn_s_setprio(0);
    __builtin_amdgcn_s_barrier();
}

__global__ __launch_bounds__(512, 2) void lstm_gemm_kernel(
    const unsigned short* __restrict__ A,   // [8192][2048] bf16
    const unsigned short* __restrict__ W,   // [1024][2048] bf16
    const float* __restrict__ Whb, const float* __restrict__ Wxb,
    const float* __restrict__ Cin,
    float* __restrict__ Hout, float* __restrict__ Cout)
{
    extern __shared__ unsigned short smem[];
    unsigned short* sA = smem;               // 3 slots of 256x64
    unsigned short* sB = smem + 3 * ASLOT;   // 3 slots of 128x64

    const int tid  = threadIdx.x;
    const int wid  = tid >> 6;
    const int lane = tid & 63;
    const int wr = wid >> 2, wc = wid & 3;          // 2M x 4N waves

    // T1 XCD-grouping: consecutive blockIdx round-robin across 8 XCDs (m09).
    // Give XCD x the bidM range [4x, 4x+4) x all bidN, so the 8 blocks sharing
    // an A-panel share one XCD's L2. Bijective on [0,256).
    const int orig = blockIdx.x;
    const int xcd  = orig & 7;
    const int loc  = orig >> 3;                     // 0..31
    const int bidM = xcd * 4 + (loc >> 3);          // 0..31
    const int bidN = loc & 7;                       // 0..7
    const int row0 = bidM * 256, col0 = bidN * 128;
    const int ln15 = lane & 15, hi = lane >> 4, ln7 = lane & 7;

    const unsigned short* Ag = A + (size_t)row0 * KTOT;
    const unsigned short* Bg = W + (size_t)col0 * KTOT;

    f32x4 acc[8][2] = {};

    // Stage one 128-row x 64-col unit: linear LDS dest (gload_lds lane x 16B),
    // inverse-swizzled global source (physical slot p holds logical slot p^(r&7)).
    auto stage = [&](const unsigned short* gbase, unsigned short* lbase) {
        #pragma unroll
        for (int j = 0; j < 2; ++j) {
            int c = j * 512 + tid;
            int r = c >> 3, p = c & 7;
            const unsigned short* g = gbase + (size_t)r * KTOT + ((p ^ (r & 7)) * 8);
            unsigned short* l = lbase + (size_t)(j * 512 + wid * 64) * 8;  // wave-uniform
            gload_lds16(g, l);
        }
    };

    // Prologue: tile 0 -> slot 0, tile 1 -> slot 1 (12 loads/thread), gate tile 0.
    stage(Ag,                           sA);
    stage(Ag + (size_t)128 * KTOT,      sA + 8192);
    stage(Bg,                           sB);
    stage(Ag + 64,                      sA + ASLOT);
    stage(Ag + (size_t)128 * KTOT + 64, sA + ASLOT + 8192);
    stage(Bg + 64,                      sB + BSLOT);
    asm volatile("s_waitcnt vmcnt(6)" ::: "memory");
    __builtin_amdgcn_s_barrier();

    int scur = 0, swr = 2;
    for (int kt = 0; kt < NKT; ++kt) {
        const unsigned short* As = sA + scur * ASLOT;
        const unsigned short* Bs = sB + scur * BSLOT;
        unsigned short* Aw = sA + swr * ASLOT;
        unsigned short* Bw = sB + swr * BSLOT;
        const size_t kn = (size_t)(kt + 2) * 64;
        const bool pre = (kt < NKT - 2);

        phase_fn<0>(As, Bs, wr, wc, ln15, hi, ln7, acc, [&] {
            if (pre) {
                stage(Ag + kn, Aw);
                stage(Ag + (size_t)128 * KTOT + kn, Aw + 8192);
            }
        });
        phase_fn<1>(As, Bs, wr, wc, ln15, hi, ln7, acc, [&] {
            if (pre) stage(Bg + kn, Bw);
            if (kt < NKT - 2)       asm volatile("s_waitcnt vmcnt(6)" ::: "memory");
            else if (kt == NKT - 2) asm volatile("s_waitcnt vmcnt(0)" ::: "memory");
        });

        scur = (scur == 2) ? 0 : scur + 1;
        swr  = (swr  == 2) ? 0 : swr  + 1;
    }

    // Epilogue: z -> (h_new, c_new). C/D map: col=lane&15, row=(lane>>4)*4+j.
    const int rlo = hi * 4;
    #pragma unroll
    for (int n = 0; n < 2; ++n) {
        const int col = col0 + wc * 32 + n * 16 + ln15;
        const float bias = Whb[col] + Wxb[col];
        #pragma unroll
        for (int m = 0; m < 8; ++m) {
            #pragma unroll
            for (int j = 0; j < 4; ++j) {
                const int row = row0 + wr * 128 + m * 16 + rlo + j;
                const size_t off = (size_t)row * DH + col;
                const float z = acc[m][n][j] + bias;
                const float s = 0.5f + 0.5f * tanh_fast(0.5f * z);  // sigmoid(z)
                const float g = tanh_fast(z);
                const float cn = s * (Cin[off] + g);
                Hout[off] = s * tanh_fast(cn);
                Cout[off] = cn;
            }
        }
    }
}

// fp32 fallback (only if workspace too small for bf16 staging)
__global__ __launch_bounds__(256) void lstm_naive_kernel(
    const float* __restrict__ x, const float* __restrict__ h,
    const float* __restrict__ c,
    const float* __restrict__ Whw, const float* __restrict__ Whb,
    const float* __restrict__ Wxw, const float* __restrict__ Wxb,
    float* __restrict__ Hout, float* __restrict__ Cout)
{
    const int idx = blockIdx.x * 256 + threadIdx.x;
    const int b = idx >> 10, n = idx & 1023;
    const float* hr = h  + (size_t)b * 1024;
    const float* xr = x  + (size_t)b * 1024;
    const float* wh = Whw + (size_t)n * 1024;
    const float* wx = Wxw + (size_t)n * 1024;
    float z = Whb[n] + Wxb[n];
    for (int k = 0; k < 1024; ++k) z += hr[k] * wh[k] + xr[k] * wx[k];
    const float s = 0.5f + 0.5f * tanh_fast(0.5f * z);
    const float g = tanh_fast(z);
    const size_t off = (size_t)b * 1024 + n;
    const float cn = s * (c[off] + g);
    Hout[off] = s * tanh_fast(cn);
    Cout[off] = cn;
}

extern "C" void kernel_launch(void* const* d_in, const int* in_sizes, int n_in,
                              void* d_out, int out_size, void* d_ws, size_t ws_size,
                              hipStream_t stream) {
    const float* x   = (const float*)d_in[0];
    const float* h   = (const float*)d_in[1];
    const float* c   = (const float*)d_in[2];
    const float* Whw = (const float*)d_in[3];
    const float* Whb = (const float*)d_in[4];
    const float* Wxw = (const float*)d_in[5];
    const float* Wxb = (const float*)d_in[6];
    float* Hout = (float*)d_out;
    float* Cout = Hout + (size_t)BATCH * DH;

    const size_t needA = (size_t)BATCH * KTOT * 2;   // 32 MiB
    const size_t needW = (size_t)DH * KTOT * 2;      //  4 MiB

    if (ws_size >= needA + needW) {
        unsigned short* Abf = (unsigned short*)d_ws;
        unsigned short* Wbf = (unsigned short*)((char*)d_ws + needA);
        cast_all_kernel<<<2304, 256, 0, stream>>>(h, x, Whw, Wxw, Abf, Wbf);
        (void)hipFuncSetAttribute((const void*)lstm_gemm_kernel,
                                  hipFuncAttributeMaxDynamicSharedMemorySize,
                                  LDS_BYTES);
        lstm_gemm_kernel<<<256, 512, LDS_BYTES, stream>>>(
            Abf, Wbf, Whb, Wxb, c, Hout, Cout);
    } else {
        lstm_naive_kernel<<<(BATCH * DH) / 256, 256, 0, stream>>>(
            x, h, c, Whw, Whb, Wxw, Wxb, Hout, Cout);
    }
}